// Round 12
// baseline (219.293 us; speedup 1.0000x reference)
//
#include <hip/hip_runtime.h>
#include <cstdint>
#include <cstddef>

// Problem constants (fixed by reference setup_inputs):
//   b=256, t=512, in_dim=30, hidden=512, n_cls=12, TAU=2, V_TH=1
#define NB 256
#define NT 512
#define IND 30
#define HID 512
#define NCLS 12
#define MAXREC 640      // per-b event record slots (16 B each, cnt<=4 per record)
#define NGRP 4          // t-chunks per b (one 256-thread block each)
#define CHUNK 128       // NT / NGRP
#define WARM 32         // warmup steps: v-error decays 0.5^32 -> ~1e-9

typedef float v2f __attribute__((ext_vector_type(2)));
typedef float v4f __attribute__((ext_vector_type(4)));
// x rows are 120 B (odd-t rows are 8 mod 16) -> only dword alignment is
// guaranteed; gfx950 global_load_dwordx4 requires only dword alignment.
typedef v4f v4f_u __attribute__((aligned(4)));
typedef v2f v2f_u __attribute__((aligned(4)));

struct XRow { v4f q[7]; v2f r; };    // one 30-float x row (8 VMEM loads)

// compile-time pair extraction (maps to pk_fma op_sel, no movs):
// pair F = floats (F, F+1) of the row; F even, F <= 26.
template<int F>
__device__ __forceinline__ v2f xpair(const XRow& X) {
    return __builtin_shufflevector(X.q[F >> 2], X.q[F >> 2], F & 3, (F & 3) + 1);
}

// ---------------------------------------------------------------------------
// lif1 + W2-transpose mega-launch: grid (NB, NGRP+1), 256 threads.
// Plane y < NGRP: layer-1 LIF scan (256-thread spill-free shape).
//   Block (b,grp) scans t in [128g-32, 128g+128); 32-step warmup from v=0
//   reconverges the recurrence (decay 0.5/step + hard resets).
//   x rows read directly from global, 8 wide loads/row (vs 15 v2f in r11 —
//   the VMEM issue stream was co-limiting), software-pipelined A/B.
// Plane y == NGRP: W2 pair-transpose (128 active blocks):
//   W2Tp[d*256 + j] = {W2[j][d], W2[j+256][d]}.
// ---------------------------------------------------------------------------
__global__ __launch_bounds__(256, 1) void lif1w_kernel(
    const float* __restrict__ x,     // (NB, NT, IND)
    const float* __restrict__ W1,    // (HID, IND)
    const float* __restrict__ b1,    // (HID)
    const float* __restrict__ W2,    // (HID, HID)
    uint64_t* __restrict__ bmg,      // (NB, NT, 8)
    v2f* __restrict__ W2Tp)          // (HID d, 256 j) pairs
{
    if (blockIdx.y == NGRP) {
        __shared__ float ta[32][33];
        __shared__ float tb[32][33];
        const int bx = blockIdx.x;
        if (bx >= (HID / 32) * (256 / 32)) return;   // 128 active blocks
        const int d0 = (bx & 15) * 32;
        const int j0 = (bx >> 4) * 32;
        const int tx = threadIdx.x & 31;
        const int ty = threadIdx.x >> 5;
        #pragma unroll
        for (int i = 0; i < 32; i += 8) {
            ta[ty + i][tx] = W2[(size_t)(j0 + ty + i) * HID + (d0 + tx)];
            tb[ty + i][tx] = W2[(size_t)(j0 + 256 + ty + i) * HID + (d0 + tx)];
        }
        __syncthreads();
        #pragma unroll
        for (int i = 0; i < 32; i += 8)
            W2Tp[(size_t)(d0 + ty + i) * 256 + (j0 + tx)]
                = v2f{ta[tx][ty + i], tb[tx][ty + i]};
        return;
    }

    // ---- layer-1 LIF scan --------------------------------------------------
    const int b    = blockIdx.x;
    const int grp  = blockIdx.y;
    const int tid  = threadIdx.x;
    const int lane = tid & 63;
    const int wg   = tid >> 6;            // wave 0..3

    v2f wA[15], wB[15];                   // j-paired W1 rows, 60 VGPRs
    {
        const v2f* pa = (const v2f*)(W1 + (size_t)tid * IND);
        const v2f* pb = (const v2f*)(W1 + (size_t)(tid + 256) * IND);
        #pragma unroll
        for (int p = 0; p < 15; p++) { wA[p] = pa[p]; wB[p] = pb[p]; }
    }
    const float biasA = b1[tid], biasB = b1[tid + 256];

    const int tmain  = grp * CHUNK;
    const int tstart = (grp == 0) ? 0 : tmain - WARM;
    const int tend   = tmain + CHUNK;
    const float* __restrict__ xb = x + (size_t)b * NT * IND;
    uint64_t* __restrict__ bout = bmg + (size_t)b * NT * 8 + wg * 2;

#define LOADROW(D, T) do {                                                \
        const float* _r = xb + (size_t)(T) * IND;                         \
        D.q[0] = *(const v4f_u*)(_r +  0);                                \
        D.q[1] = *(const v4f_u*)(_r +  4);                                \
        D.q[2] = *(const v4f_u*)(_r +  8);                                \
        D.q[3] = *(const v4f_u*)(_r + 12);                                \
        D.q[4] = *(const v4f_u*)(_r + 16);                                \
        D.q[5] = *(const v4f_u*)(_r + 20);                                \
        D.q[6] = *(const v4f_u*)(_r + 24);                                \
        D.r    = *(const v2f_u*)(_r + 28);                                \
    } while (0)

    // pair p (p=0..13) uses acc index p%3 — same mapping & reduce order as
    // r11 (bit-identical z).
#define MACP(X, P)                                                        \
        { const v2f _xp = xpair<2*(P)>(X);                                \
          aA[(P) % 3] = __builtin_elementwise_fma(_xp, wA[P], aA[(P) % 3]); \
          aB[(P) % 3] = __builtin_elementwise_fma(_xp, wB[P], aB[(P) % 3]); }

#define LIF_STEP(X, T) do {                                               \
        v2f aA[3] = {{biasA, 0.f}, {0.f, 0.f}, {0.f, 0.f}};               \
        v2f aB[3] = {{biasB, 0.f}, {0.f, 0.f}, {0.f, 0.f}};               \
        MACP(X, 0)  MACP(X, 1)  MACP(X, 2)  MACP(X, 3)  MACP(X, 4)        \
        MACP(X, 5)  MACP(X, 6)  MACP(X, 7)  MACP(X, 8)  MACP(X, 9)        \
        MACP(X, 10) MACP(X, 11) MACP(X, 12) MACP(X, 13)                   \
        aA[2] = __builtin_elementwise_fma(X.r, wA[14], aA[2]);            \
        aB[2] = __builtin_elementwise_fma(X.r, wB[14], aB[2]);            \
        const v2f sA = (aA[0] + aA[1]) + aA[2];                           \
        const v2f sB = (aB[0] + aB[1]) + aB[2];                           \
        const float zA = sA.x + sA.y;                                     \
        const float zB = sB.x + sB.y;                                     \
        vA = vA + (zA - vA) * 0.5f;       /* charge (tau=2) */            \
        vB = vB + (zB - vB) * 0.5f;                                       \
        const bool s0 = vA >= 1.0f;                                       \
        const bool s1 = vB >= 1.0f;                                       \
        const unsigned long long m0 = __ballot(s0);                       \
        const unsigned long long m1 = __ballot(s1);                       \
        if (s0) vA = 0.0f;                                                \
        if (s1) vB = 0.0f;                                                \
        if ((T) >= tmain && lane == 0) {                                  \
            ulonglong2 st; st.x = m0; st.y = m1;                          \
            *(ulonglong2*)(bout + (size_t)(T) * 8) = st;                  \
        }                                                                 \
    } while (0)

    float vA = 0.f, vB = 0.f;
    XRow XA, XB;
    LOADROW(XA, tstart);
    for (int t = tstart; t < tend; t += 2) {
        LOADROW(XB, t + 1);                           // t+1 <= tend-1 <= 511
        LIF_STEP(XA, t);
        const int t2 = (t + 2 < NT) ? t + 2 : NT - 2; // clamp final prefetch
        LOADROW(XA, t2);
        LIF_STEP(XB, t + 1);
    }
#undef LIF_STEP
#undef MACP
#undef LOADROW
}

// ---------------------------------------------------------------------------
// tail: per-b, 256 threads (the spill-free RA shape — r10's part 2, which
// ran at VGPR=60 with zero scratch). pack bitmap -> event records ->
// event-driven layer-2 LIF over the full timeline (exact) -> head GEMV.
// Bitmap word wi covers h = (wi>>1)*64 + (wi&1)*256 + bit (paired stores).
// ---------------------------------------------------------------------------
__global__ __launch_bounds__(256, 1) void snn_tail_kernel(
    const uint64_t* __restrict__ bmg, // (NB, NT, 8)
    const v2f*  __restrict__ W2Tp,    // (HID d, 256 j) pairs
    const float* __restrict__ b2,     // (HID)
    const float* __restrict__ Wh,     // (NCLS, HID)
    const float* __restrict__ bh,     // (NCLS)
    float* __restrict__ out)          // (NB, NCLS)
{
    __shared__ uint32_t sbuf[2][NT];      // 4 KB record-count scan
    __shared__ uint4    evl[MAXREC];      // 10 KB packed event records
    __shared__ float    feat[HID];        // 2 KB
    __shared__ uint32_t nrec_s;

    const int b    = blockIdx.x;
    const int tid  = threadIdx.x;
    const int lane = tid & 63;
    const int wg   = tid >> 6;
    const int t0 = tid, t1 = tid + 256;

    // ---- pack: bitmap -> event records ------------------------------------
    uint64_t w0[8], w1[8];
    {
        const uint4* p0 = (const uint4*)(bmg + ((size_t)b * NT + t0) * 8);
        const uint4* p1 = (const uint4*)(bmg + ((size_t)b * NT + t1) * 8);
        #pragma unroll
        for (int k = 0; k < 4; k++) {
            const uint4 qa = p0[k];
            w0[2 * k]     = (uint64_t)qa.x | ((uint64_t)qa.y << 32);
            w0[2 * k + 1] = (uint64_t)qa.z | ((uint64_t)qa.w << 32);
            const uint4 qb = p1[k];
            w1[2 * k]     = (uint64_t)qb.x | ((uint64_t)qb.y << 32);
            w1[2 * k + 1] = (uint64_t)qb.z | ((uint64_t)qb.w << 32);
        }
    }
    int c0 = 0, c1 = 0;
    #pragma unroll
    for (int k = 0; k < 8; k++) { c0 += __builtin_popcountll(w0[k]); c1 += __builtin_popcountll(w1[k]); }
    const int r0 = (c0 + 3) >> 2;
    const int r1 = (c1 + 3) >> 2;

    sbuf[0][t0] = (uint32_t)r0; sbuf[0][t1] = (uint32_t)r1;
    __syncthreads();
    int cur = 0;
    for (int off = 1; off < NT; off <<= 1) {
        const uint32_t a = sbuf[cur][t0] + (t0 >= off ? sbuf[cur][t0 - off] : 0u);
        const uint32_t c = sbuf[cur][t1] + (t1 >= off ? sbuf[cur][t1 - off] : 0u);
        sbuf[cur ^ 1][t0] = a; sbuf[cur ^ 1][t1] = c;
        __syncthreads();
        cur ^= 1;
    }
    const int excl0 = (int)sbuf[cur][t0] - r0;
    const int excl1 = (int)sbuf[cur][t1] - r1;
    if (tid == 0) nrec_s = sbuf[cur][NT - 1];

    auto emit = [&](const uint64_t* wv, int t, int slot) {
        int kk = 0; uint64_t ww = 0;
        #pragma unroll
        for (int wi = 0; wi < 8; wi++) {
            uint64_t wd = wv[wi];
            const int hbase = ((wi >> 1) << 6) + ((wi & 1) << 8);  // paired words
            while (wd) {
                const int d = hbase + __builtin_ctzll(wd);
                wd &= wd - 1;
                ww |= (uint64_t)(uint32_t)d << (kk * 16);
                kk++;
                if (kk == 4) {
                    if (slot < MAXREC) {
                        uint4 q; q.x = (uint32_t)(t | (4 << 16)); q.y = 0;
                        q.z = (uint32_t)ww; q.w = (uint32_t)(ww >> 32);
                        evl[slot] = q;
                    }
                    slot++; kk = 0; ww = 0;
                }
            }
        }
        if (kk) {
            if (slot < MAXREC) {
                uint4 q; q.x = (uint32_t)(t | (kk << 16)); q.y = 0;
                q.z = (uint32_t)ww; q.w = (uint32_t)(ww >> 32);
                evl[slot] = q;
            }
        }
    };
    emit(w0, t0, excl0);
    emit(w1, t1, excl1);
    __syncthreads();

    // ---- event-driven layer-2 LIF, full timeline (exact) ------------------
    const int nrec = (int)nrec_s < MAXREC ? (int)nrec_s : MAXREC;
    {
        const float bb0 = b2[tid], bb1 = b2[tid + 256];
        float v0 = 0.f, v1 = 0.f;
        int cnt0 = 0, cnt1 = 0;
        int tprev = -1;
        int pt = -1; v2f pg = {0.f, 0.f}; bool pend = false;

#define APPLY() do {                                                      \
        const int kk = pt - tprev - 1;                                    \
        if (kk > 0) { v0 = bb0 + ldexpf(v0 - bb0, -kk);                   \
                      v1 = bb1 + ldexpf(v1 - bb1, -kk); }                 \
        const float z0 = pg.x + bb0, z1 = pg.y + bb1;                     \
        v0 = v0 + (z0 - v0) * 0.5f;                                       \
        v1 = v1 + (z1 - v1) * 0.5f;                                       \
        if (v0 >= 1.0f) { cnt0++; v0 = 0.0f; }                            \
        if (v1 >= 1.0f) { cnt1++; v1 = 0.0f; }                            \
        tprev = pt;                                                       \
    } while (0)

        for (int base = 0; base < nrec; base += 16) {
            v2f g[16]; int tt[16];
            #pragma unroll
            for (int q = 0; q < 16; q++) {
                v2f gr = {0.f, 0.f}; int trr = -2;
                if (base + q < nrec) {
                    const uint4 ev = evl[base + q];       // uniform LDS read
                    trr = (int)(ev.x & 511u);
                    const int cc = (int)((ev.x >> 16) & 7u);
                    const uint64_t ww = (uint64_t)ev.z | ((uint64_t)ev.w << 32);
                    #pragma unroll
                    for (int j = 0; j < 4; j++) {
                        const int d = (int)((ww >> (16 * j)) & 0xffffu);
                        const float m = (j < cc) ? 1.0f : 0.0f;
                        const v2f wvv = W2Tp[(size_t)d * 256 + tid];  // always issued
                        gr = gr + v2f{m, m} * wvv;
                    }
                }
                g[q] = gr; tt[q] = trr;
            }
            #pragma unroll
            for (int q = 0; q < 16; q++) {
                if (base + q >= nrec) break;
                const int t = tt[q];
                if (pend && t == pt) { pg = pg + g[q]; }
                else { if (pend) APPLY(); pt = t; pg = g[q]; pend = true; }
            }
        }
        if (pend) APPLY();
#undef APPLY

        feat[tid]       = (float)cnt0 * (1.0f / (float)NT);
        feat[tid + 256] = (float)cnt1 * (1.0f / (float)NT);
    }
    __syncthreads();

    // ---- head: wave wg computes classes 3wg..3wg+2 ------------------------
    float acc[3] = {0.f, 0.f, 0.f};
    #pragma unroll
    for (int i = 0; i < HID / 64; i++) {
        const float f = feat[lane + i * 64];
        #pragma unroll
        for (int cc = 0; cc < 3; cc++)
            acc[cc] = fmaf(f, Wh[(size_t)(wg * 3 + cc) * HID + lane + i * 64], acc[cc]);
    }
    #pragma unroll
    for (int cc = 0; cc < 3; cc++) {
        float s = acc[cc];
        #pragma unroll
        for (int off = 32; off > 0; off >>= 1) s += __shfl_down(s, off);
        if (lane == 0) out[(size_t)b * NCLS + wg * 3 + cc] = s + bh[wg * 3 + cc];
    }
}

// ---------------------------------------------------------------------------
extern "C" void kernel_launch(void* const* d_in, const int* in_sizes, int n_in,
                              void* d_out, int out_size, void* d_ws, size_t ws_size,
                              hipStream_t stream) {
    const float* x  = (const float*)d_in[0];
    const float* W1 = (const float*)d_in[1];
    const float* b1 = (const float*)d_in[2];
    const float* W2 = (const float*)d_in[3];
    const float* b2 = (const float*)d_in[4];
    const float* Wh = (const float*)d_in[5];
    const float* bh = (const float*)d_in[6];
    float* out = (float*)d_out;

    // Workspace: W2Tp (1 MB) + global spike bitmap (8 MB).
    char* ws = (char*)d_ws;
    v2f*      W2Tp = (v2f*)ws;
    uint64_t* bmg  = (uint64_t*)(ws + (1u << 20));

    hipLaunchKernelGGL(lif1w_kernel, dim3(NB, NGRP + 1), dim3(256), 0, stream,
                       x, W1, b1, W2, bmg, W2Tp);
    hipLaunchKernelGGL(snn_tail_kernel, dim3(NB), dim3(256), 0, stream,
                       bmg, W2Tp, b2, Wh, bh, out);
}

// Round 13
// 144.768 us; speedup vs baseline: 1.5148x; 1.5148x over previous
//
#include <hip/hip_runtime.h>
#include <cstdint>
#include <cstddef>

// Problem constants (fixed by reference setup_inputs):
//   b=256, t=512, in_dim=30, hidden=512, n_cls=12, TAU=2, V_TH=1
#define NB 256
#define NT 512
#define IND 30
#define HID 512
#define NCLS 12
#define NGRP 4          // t-chunks per b
#define CHUNK 128       // NT / NGRP
#define WARM 32         // warmup steps: v-error decays 0.5^32 -> ~1e-9
#define LMAXREC 576     // per-(b,grp) local event record slots

typedef float v2f __attribute__((ext_vector_type(2)));
typedef float v4f __attribute__((ext_vector_type(4)));
// x rows are 120 B (odd-t rows are 8 mod 16) -> only dword alignment is
// guaranteed; gfx950 global_load_dwordx4 requires only dword alignment.
typedef v4f v4f_u __attribute__((aligned(4)));
typedef v2f v2f_u __attribute__((aligned(4)));

struct XRow { v4f q[7]; v2f r; };    // one 30-float x row (8 VMEM loads)

template<int F>
__device__ __forceinline__ v2f xpair(const XRow& X) {
    return __builtin_shufflevector(X.q[F >> 2], X.q[F >> 2], F & 3, (F & 3) + 1);
}

// ---------------------------------------------------------------------------
// lif1 + W2-transpose + gfeat-zero mega-launch: grid (NB, NGRP+1), 256 thr.
// Plane y < NGRP: layer-1 LIF scan, 4-row software pipeline (loads issued
//   ~2 steps / ~180 cyc ahead of use -> covers L2 latency that bounded r11).
//   Block (b,grp) scans t in [128g-32, 128g+128); 32-step warmup from v=0
//   reconverges the recurrence (decay 0.5/step + hard resets).
// Plane y == NGRP: zero gfeat (all 256 blocks) + W2 pair-transpose
//   (blocks 0..127): W2Tp[d*256 + j] = {W2[j][d], W2[j+256][d]}.
// ---------------------------------------------------------------------------
__global__ __launch_bounds__(256, 1) void lif1w_kernel(
    const float* __restrict__ x,     // (NB, NT, IND)
    const float* __restrict__ W1,    // (HID, IND)
    const float* __restrict__ b1,    // (HID)
    const float* __restrict__ W2,    // (HID, HID)
    uint64_t* __restrict__ bmg,      // (NB, NT, 8)
    v2f* __restrict__ W2Tp,          // (HID d, 256 j) pairs
    float* __restrict__ gfeat)       // (NB, HID) spike-count accumulator
{
    if (blockIdx.y == NGRP) {
        const int bx = blockIdx.x;
        // zero the atomic accumulation target (stream-ordered before tail)
        gfeat[(size_t)bx * HID + threadIdx.x] = 0.f;
        gfeat[(size_t)bx * HID + 256 + threadIdx.x] = 0.f;
        if (bx >= (HID / 32) * (256 / 32)) return;   // 128 transpose blocks
        __shared__ float ta[32][33];
        __shared__ float tb[32][33];
        const int d0 = (bx & 15) * 32;
        const int j0 = (bx >> 4) * 32;
        const int tx = threadIdx.x & 31;
        const int ty = threadIdx.x >> 5;
        #pragma unroll
        for (int i = 0; i < 32; i += 8) {
            ta[ty + i][tx] = W2[(size_t)(j0 + ty + i) * HID + (d0 + tx)];
            tb[ty + i][tx] = W2[(size_t)(j0 + 256 + ty + i) * HID + (d0 + tx)];
        }
        __syncthreads();
        #pragma unroll
        for (int i = 0; i < 32; i += 8)
            W2Tp[(size_t)(d0 + ty + i) * 256 + (j0 + tx)]
                = v2f{ta[tx][ty + i], tb[tx][ty + i]};
        return;
    }

    // ---- layer-1 LIF scan --------------------------------------------------
    const int b    = blockIdx.x;
    const int grp  = blockIdx.y;
    const int tid  = threadIdx.x;
    const int lane = tid & 63;
    const int wg   = tid >> 6;            // wave 0..3

    v2f wA[15], wB[15];                   // j-paired W1 rows, 60 VGPRs
    {
        const v2f* pa = (const v2f*)(W1 + (size_t)tid * IND);
        const v2f* pb = (const v2f*)(W1 + (size_t)(tid + 256) * IND);
        #pragma unroll
        for (int p = 0; p < 15; p++) { wA[p] = pa[p]; wB[p] = pb[p]; }
    }
    const float biasA = b1[tid], biasB = b1[tid + 256];

    const int tmain  = grp * CHUNK;
    const int tstart = (grp == 0) ? 0 : tmain - WARM;
    const int tend   = tmain + CHUNK;
    const float* __restrict__ xb = x + (size_t)b * NT * IND;
    uint64_t* __restrict__ bout = bmg + (size_t)b * NT * 8 + wg * 2;

#define LOADROW(D, T) do {                                                \
        const float* _r = xb + (size_t)(T) * IND;                         \
        D.q[0] = *(const v4f_u*)(_r +  0);                                \
        D.q[1] = *(const v4f_u*)(_r +  4);                                \
        D.q[2] = *(const v4f_u*)(_r +  8);                                \
        D.q[3] = *(const v4f_u*)(_r + 12);                                \
        D.q[4] = *(const v4f_u*)(_r + 16);                                \
        D.q[5] = *(const v4f_u*)(_r + 20);                                \
        D.q[6] = *(const v4f_u*)(_r + 24);                                \
        D.r    = *(const v2f_u*)(_r + 28);                                \
    } while (0)

#define MACP(X, P)                                                        \
        { const v2f _xp = xpair<2*(P)>(X);                                \
          aA[(P) % 3] = __builtin_elementwise_fma(_xp, wA[P], aA[(P) % 3]); \
          aB[(P) % 3] = __builtin_elementwise_fma(_xp, wB[P], aB[(P) % 3]); }

#define LIF_STEP(X, T) do {                                               \
        v2f aA[3] = {{biasA, 0.f}, {0.f, 0.f}, {0.f, 0.f}};               \
        v2f aB[3] = {{biasB, 0.f}, {0.f, 0.f}, {0.f, 0.f}};               \
        MACP(X, 0)  MACP(X, 1)  MACP(X, 2)  MACP(X, 3)  MACP(X, 4)        \
        MACP(X, 5)  MACP(X, 6)  MACP(X, 7)  MACP(X, 8)  MACP(X, 9)        \
        MACP(X, 10) MACP(X, 11) MACP(X, 12) MACP(X, 13)                   \
        aA[2] = __builtin_elementwise_fma(X.r, wA[14], aA[2]);            \
        aB[2] = __builtin_elementwise_fma(X.r, wB[14], aB[2]);            \
        const v2f sA = (aA[0] + aA[1]) + aA[2];                           \
        const v2f sB = (aB[0] + aB[1]) + aB[2];                           \
        const float zA = sA.x + sA.y;                                     \
        const float zB = sB.x + sB.y;                                     \
        vA = vA + (zA - vA) * 0.5f;       /* charge (tau=2) */            \
        vB = vB + (zB - vB) * 0.5f;                                       \
        const bool s0 = vA >= 1.0f;                                       \
        const bool s1 = vB >= 1.0f;                                       \
        const unsigned long long m0 = __ballot(s0);                       \
        const unsigned long long m1 = __ballot(s1);                       \
        if (s0) vA = 0.0f;                                                \
        if (s1) vB = 0.0f;                                                \
        if ((T) >= tmain && lane == 0) {                                  \
            ulonglong2 st; st.x = m0; st.y = m1;                          \
            *(ulonglong2*)(bout + (size_t)(T) * 8) = st;                  \
        }                                                                 \
    } while (0)

    float vA = 0.f, vB = 0.f;
    XRow X0, X1, X2, X3;                  // 4-row pipeline, ~2-step lookahead
    LOADROW(X0, tstart);
    LOADROW(X1, tstart + 1);
    for (int t = tstart; t < tend; t += 4) {
        LOADROW(X2, t + 2);               // t+3 <= tend-1 <= 511 always
        LOADROW(X3, t + 3);
        LIF_STEP(X0, t);
        LIF_STEP(X1, t + 1);
        const int t4 = (t + 4 < tend) ? t + 4 : NT - 2;   // clamp final loads
        const int t5 = (t + 5 < tend) ? t + 5 : NT - 1;
        LOADROW(X0, t4);
        LOADROW(X1, t5);
        LIF_STEP(X2, t + 2);
        LIF_STEP(X3, t + 3);
    }
#undef LIF_STEP
#undef MACP
#undef LOADROW
}

// ---------------------------------------------------------------------------
// tail: grid (NB, NGRP), 256 threads — 1024 blocks = 16 waves/CU (the r12
// 1-block/CU tail serialized ~2000 dependent L2 gathers with nothing to
// hide them). Block (b,grp) packs ONLY its rows [tmain-32, tmain+128) into
// local LDS event records, event-scans layer-2 with the warmup-reconverged
// recurrence, and atomically accumulates integer spike counts into gfeat
// (float adds of integers: exact).
// Bitmap word wi covers h = (wi>>1)*64 + (wi&1)*256 + bit (paired stores).
// ---------------------------------------------------------------------------
__global__ __launch_bounds__(256, 1) void tail_kernel(
    const uint64_t* __restrict__ bmg, // (NB, NT, 8)
    const v2f*  __restrict__ W2Tp,    // (HID d, 256 j) pairs
    const float* __restrict__ b2,     // (HID)
    float* __restrict__ gfeat)        // (NB, HID) accumulator
{
    __shared__ uint32_t sbuf[2][256];
    __shared__ uint4    evl[LMAXREC];     // 9 KB local event records
    __shared__ uint32_t nrec_s;

    const int b     = blockIdx.x;
    const int grp   = blockIdx.y;
    const int tid   = threadIdx.x;
    const int tmain = grp * CHUNK;
    const int ts    = (grp == 0) ? 0 : tmain - WARM;
    const int te    = tmain + CHUNK;
    const int nrow  = te - ts;            // 128 or 160

    // ---- pack local rows -> event records ---------------------------------
    uint64_t w0[8];
    int rcnt = 0;
    if (tid < nrow) {
        const uint4* p = (const uint4*)(bmg + ((size_t)b * NT + ts + tid) * 8);
        int cpop = 0;
        #pragma unroll
        for (int k = 0; k < 4; k++) {
            const uint4 q = p[k];
            w0[2 * k]     = (uint64_t)q.x | ((uint64_t)q.y << 32);
            w0[2 * k + 1] = (uint64_t)q.z | ((uint64_t)q.w << 32);
        }
        #pragma unroll
        for (int k = 0; k < 8; k++) cpop += __builtin_popcountll(w0[k]);
        rcnt = (cpop + 3) >> 2;
    }
    sbuf[0][tid] = (uint32_t)rcnt;
    __syncthreads();
    int cur = 0;
    for (int off = 1; off < 256; off <<= 1) {
        const uint32_t a = sbuf[cur][tid] + (tid >= off ? sbuf[cur][tid - off] : 0u);
        sbuf[cur ^ 1][tid] = a;
        __syncthreads();
        cur ^= 1;
    }
    const int excl = (int)sbuf[cur][tid] - rcnt;
    if (tid == 255) nrec_s = sbuf[cur][255];

    if (tid < nrow && rcnt) {
        const int t = ts + tid;
        int slot = excl, kk = 0; uint64_t ww = 0;
        #pragma unroll
        for (int wi = 0; wi < 8; wi++) {
            uint64_t wd = w0[wi];
            const int hbase = ((wi >> 1) << 6) + ((wi & 1) << 8);  // paired words
            while (wd) {
                const int d = hbase + __builtin_ctzll(wd);
                wd &= wd - 1;
                ww |= (uint64_t)(uint32_t)d << (kk * 16);
                kk++;
                if (kk == 4) {
                    if (slot < LMAXREC) {
                        uint4 q; q.x = (uint32_t)(t | (4 << 16)); q.y = 0;
                        q.z = (uint32_t)ww; q.w = (uint32_t)(ww >> 32);
                        evl[slot] = q;
                    }
                    slot++; kk = 0; ww = 0;
                }
            }
        }
        if (kk && slot < LMAXREC) {
            uint4 q; q.x = (uint32_t)(t | (kk << 16)); q.y = 0;
            q.z = (uint32_t)ww; q.w = (uint32_t)(ww >> 32);
            evl[slot] = q;
        }
    }
    __syncthreads();

    // ---- event-driven layer-2 LIF over this group's range -----------------
    const int nrec = (int)nrec_s < LMAXREC ? (int)nrec_s : LMAXREC;
    const float bb0 = b2[tid], bb1 = b2[tid + 256];
    float v0 = 0.f, v1 = 0.f;
    int cnt0 = 0, cnt1 = 0;
    int tprev = ts - 1;
    int pt = -1; v2f pg = {0.f, 0.f}; bool pend = false;

#define APPLY() do {                                                      \
        const int kk = pt - tprev - 1;                                    \
        if (kk > 0) { v0 = bb0 + ldexpf(v0 - bb0, -kk);                   \
                      v1 = bb1 + ldexpf(v1 - bb1, -kk); }                 \
        const float z0 = pg.x + bb0, z1 = pg.y + bb1;                     \
        v0 = v0 + (z0 - v0) * 0.5f;                                       \
        v1 = v1 + (z1 - v1) * 0.5f;                                       \
        if (v0 >= 1.0f) { if (pt >= tmain) cnt0++; v0 = 0.0f; }           \
        if (v1 >= 1.0f) { if (pt >= tmain) cnt1++; v1 = 0.0f; }           \
        tprev = pt;                                                       \
    } while (0)

    for (int base = 0; base < nrec; base += 8) {
        v2f g[8]; int tt[8];
        #pragma unroll
        for (int q = 0; q < 8; q++) {
            v2f gr = {0.f, 0.f}; int trr = -2;
            if (base + q < nrec) {
                const uint4 ev = evl[base + q];           // uniform LDS read
                trr = (int)(ev.x & 511u);
                const int cc = (int)((ev.x >> 16) & 7u);
                const uint64_t ww = (uint64_t)ev.z | ((uint64_t)ev.w << 32);
                #pragma unroll
                for (int j = 0; j < 4; j++) {
                    const int d = (int)((ww >> (16 * j)) & 0xffffu);
                    const float m = (j < cc) ? 1.0f : 0.0f;
                    const v2f wv = W2Tp[(size_t)d * 256 + tid];  // always issued
                    gr = gr + v2f{m, m} * wv;
                }
            }
            g[q] = gr; tt[q] = trr;
        }
        #pragma unroll
        for (int q = 0; q < 8; q++) {
            if (base + q >= nrec) break;
            const int t = tt[q];
            if (pend && t == pt) { pg = pg + g[q]; }
            else { if (pend) APPLY(); pt = t; pg = g[q]; pend = true; }
        }
    }
    if (pend) APPLY();
#undef APPLY

    if (cnt0) atomicAdd(&gfeat[(size_t)b * HID + tid], (float)cnt0);
    if (cnt1) atomicAdd(&gfeat[(size_t)b * HID + 256 + tid], (float)cnt1);
}

// ---------------------------------------------------------------------------
// head: out = (gfeat/NT) @ Wh^T + bh. Grid NB, 256 threads.
// ---------------------------------------------------------------------------
__global__ __launch_bounds__(256) void head_kernel(
    const float* __restrict__ gfeat, // (NB, HID)
    const float* __restrict__ Wh,    // (NCLS, HID)
    const float* __restrict__ bh,    // (NCLS)
    float* __restrict__ out)         // (NB, NCLS)
{
    __shared__ float feat[HID];
    const int b = blockIdx.x;
    const int tid = threadIdx.x;
    const int lane = tid & 63;
    const int wg = tid >> 6;

    feat[tid]       = gfeat[(size_t)b * HID + tid]       * (1.0f / (float)NT);
    feat[tid + 256] = gfeat[(size_t)b * HID + 256 + tid] * (1.0f / (float)NT);
    __syncthreads();

    float acc[3] = {0.f, 0.f, 0.f};
    #pragma unroll
    for (int i = 0; i < HID / 64; i++) {
        const float f = feat[lane + i * 64];
        #pragma unroll
        for (int cc = 0; cc < 3; cc++)
            acc[cc] = fmaf(f, Wh[(size_t)(wg * 3 + cc) * HID + lane + i * 64], acc[cc]);
    }
    #pragma unroll
    for (int cc = 0; cc < 3; cc++) {
        float s = acc[cc];
        #pragma unroll
        for (int off = 32; off > 0; off >>= 1) s += __shfl_down(s, off);
        if (lane == 0) out[(size_t)b * NCLS + wg * 3 + cc] = s + bh[wg * 3 + cc];
    }
}

// ---------------------------------------------------------------------------
extern "C" void kernel_launch(void* const* d_in, const int* in_sizes, int n_in,
                              void* d_out, int out_size, void* d_ws, size_t ws_size,
                              hipStream_t stream) {
    const float* x  = (const float*)d_in[0];
    const float* W1 = (const float*)d_in[1];
    const float* b1 = (const float*)d_in[2];
    const float* W2 = (const float*)d_in[3];
    const float* b2 = (const float*)d_in[4];
    const float* Wh = (const float*)d_in[5];
    const float* bh = (const float*)d_in[6];
    float* out = (float*)d_out;

    // Workspace: W2Tp (1 MB) + bitmap (8 MB) + gfeat (512 KB).
    char* ws = (char*)d_ws;
    v2f*      W2Tp  = (v2f*)ws;
    uint64_t* bmg   = (uint64_t*)(ws + (1u << 20));
    float*    gfeat = (float*)(ws + (9u << 20));

    hipLaunchKernelGGL(lif1w_kernel, dim3(NB, NGRP + 1), dim3(256), 0, stream,
                       x, W1, b1, W2, bmg, W2Tp, gfeat);
    hipLaunchKernelGGL(tail_kernel, dim3(NB, NGRP), dim3(256), 0, stream,
                       bmg, W2Tp, b2, gfeat);
    hipLaunchKernelGGL(head_kernel, dim3(NB), dim3(256), 0, stream,
                       gfeat, Wh, bh, out);
}

// Round 14
// 121.553 us; speedup vs baseline: 1.8041x; 1.1910x over previous
//
#include <hip/hip_runtime.h>
#include <cstdint>
#include <cstddef>

// Problem constants (fixed by reference setup_inputs):
//   b=256, t=512, in_dim=30, hidden=512, n_cls=12, TAU=2, V_TH=1
#define NB 256
#define NT 512
#define IND 30
#define HID 512
#define NCLS 12
#define NGRP 4          // t-chunks for the layer-2 tail
#define CHUNK 128       // NT / NGRP
#define WARM 32         // tail warmup steps: 0.5^32 reconvergence
#define LMAXREC 576     // per-(b,grp) local event record slots
#define TS 32           // lif1 stripe size (t)
#define NSTR (NT / TS)  // 16 stripes

typedef float v2f __attribute__((ext_vector_type(2)));
typedef float v4f __attribute__((ext_vector_type(4)));
typedef short s8v __attribute__((ext_vector_type(8)));   // 8 bf16 = 4 VGPRs

// f32 -> bf16 (RNE), and exact remainder
__device__ __forceinline__ uint16_t bf16_rne(float x) {
    uint32_t u = __float_as_uint(x);
    return (uint16_t)((u + 0x7fffu + ((u >> 16) & 1u)) >> 16);
}
__device__ __forceinline__ float bf16_to_f32(uint16_t h) {
    return __uint_as_float((uint32_t)h << 16);
}

// ---------------------------------------------------------------------------
// w2pt: W2 pair-transpose + gfeat zeroing.
// W2Tp[d*256 + j] = {W2[j][d], W2[j+256][d]}; grid (16,8); block flat id f
// zeros gfeat rows 2f, 2f+1 (stream-ordered before tail's atomics).
// ---------------------------------------------------------------------------
__global__ __launch_bounds__(256) void w2pt_kernel(
    const float* __restrict__ W2, v2f* __restrict__ W2Tp,
    float* __restrict__ gfeat)
{
    __shared__ float ta[32][33];
    __shared__ float tb[32][33];
    const int flat = blockIdx.y * 16 + blockIdx.x;   // 0..127
    {   // zero 2 gfeat rows (256*512 total / 128 blocks)
        float* g = gfeat + (size_t)flat * 2 * HID;
        g[threadIdx.x] = 0.f; g[threadIdx.x + 256] = 0.f;
        g[threadIdx.x + 512] = 0.f; g[threadIdx.x + 768] = 0.f;
    }
    const int d0 = blockIdx.x * 32;
    const int j0 = blockIdx.y * 32;
    const int tx = threadIdx.x & 31;
    const int ty = threadIdx.x >> 5;
    #pragma unroll
    for (int i = 0; i < 32; i += 8) {
        ta[ty + i][tx] = W2[(size_t)(j0 + ty + i) * HID + (d0 + tx)];
        tb[ty + i][tx] = W2[(size_t)(j0 + 256 + ty + i) * HID + (d0 + tx)];
    }
    __syncthreads();
    #pragma unroll
    for (int i = 0; i < 32; i += 8)
        W2Tp[(size_t)(d0 + ty + i) * 256 + (j0 + tx)] = v2f{ta[tx][ty + i], tb[tx][ty + i]};
}

// ---------------------------------------------------------------------------
// lif1 via MFMA: one block (512 thr, 8 waves) per b.
// z[t][h] = x.W1^T + b1 computed in 16x16x32 bf16 MFMA with split precision
// (x=xh+xl, W=wh+wl; 3 terms; |dz| ~1e-5 — harmless, layer-2 margin >= 0.5).
// Fragment conventions (only lane&15 = M/N index and the VERIFIED C/D map
// col=lane&15,row=(lane>>4)*4+reg are HW assumptions; k-slot assignment
// k = (lane>>4)*8 + j is consistent between A and B so the K-sum is exact
// under any internal HW k-order):
//   A (x, 16t x 32k):  lane holds row (lane&15), k-slots (lane>>4)*8+j
//   B (W1^T, 32k x 16h): lane holds col (lane&15), same k-slots
//   D: t = tt*16 + (lane>>4)*4 + reg, h = ht*16 + (lane&15)
// Wave w owns h-tiles 4w..4w+3; its W-frags (32 VGPR) persist all stripes.
// Per 32-t stripe: stage x->bf16 frags in LDS (dbuf), 24 MFMA, acc->z_lds
// [h][36], scan thread h reads its row as 8 b128 -> 32 pure-VALU LIF steps
// (overlapped with next stripe's GEMM). Spike ballots -> global bitmap,
// natural word order (word = h>>6). No layer-1 time split; v exact-serial.
// ---------------------------------------------------------------------------
__global__ __launch_bounds__(512, 1)
__attribute__((amdgpu_waves_per_eu(1, 2)))
void lif1_mfma_kernel(
    const float* __restrict__ x,     // (NB, NT, IND)
    const float* __restrict__ W1,    // (HID, IND)
    const float* __restrict__ b1,    // (HID)
    uint64_t* __restrict__ bmg)      // (NB, NT, 8)
{
    __shared__ __align__(16) short xfr[2][2][1024];  // 8 KB [buf][hi/lo][frag]
    __shared__ __align__(16) float zl[HID][36];      // 72 KB, stride 36 (16B-aligned rows)

    const int b    = blockIdx.x;
    const int tid  = threadIdx.x;
    const int lane = tid & 63;
    const int w    = tid >> 6;            // wave 0..7
    const int kg   = lane >> 4;           // k-group 0..3
    const int m16  = lane & 15;

    // ---- one-time: W1 b-frags (hi/lo) + bias for this wave's 4 h-tiles ----
    s8v whi[4], wlo[4];
    float biasv[4];
    #pragma unroll
    for (int i = 0; i < 4; i++) {
        const int h = (w * 4 + i) * 16 + m16;
        const float* wr = W1 + (size_t)h * IND;
        biasv[i] = b1[h];
        #pragma unroll
        for (int j = 0; j < 8; j++) {
            const int k = kg * 8 + j;
            const float wv = (k < IND) ? wr[k] : 0.f;
            const uint16_t hi = bf16_rne(wv);
            const float rem = wv - bf16_to_f32(hi);   // exact (Sterbenz)
            whi[i][j] = (short)hi;
            wlo[i][j] = (short)bf16_rne(rem);
        }
    }

    const float* __restrict__ xb = x + (size_t)b * NT * IND;
    uint64_t* __restrict__ bout = bmg + (size_t)b * NT * 8 + w;

    // stage stripe s (t0 = s*TS) into xfr[bs]: frag-order bf16 hi/lo.
    // element e: t_local = e>>5, k = e&31 (k>=30 -> zero pad).
#define STAGE(S, BS) do {                                                 \
        const int _t0 = (S) * TS;                                         \
        _Pragma("unroll")                                                 \
        for (int _p = 0; _p < 2; _p++) {                                  \
            const int _e = tid + _p * 512;                                \
            const int _tl = _e >> 5, _k = _e & 31;                        \
            const float _xv = (_k < IND)                                  \
                ? xb[(size_t)(_t0 + _tl) * IND + _k] : 0.f;               \
            const uint16_t _hi = bf16_rne(_xv);                           \
            const float _rm = _xv - bf16_to_f32(_hi);                     \
            const uint16_t _lo = bf16_rne(_rm);                           \
            const int _off = (((_tl >> 4) * 4 + (_k >> 3)) * 16           \
                              + (_tl & 15)) * 8 + (_k & 7);               \
            xfr[BS][0][_off] = (short)_hi;                                \
            xfr[BS][1][_off] = (short)_lo;                                \
        }                                                                 \
    } while (0)

    v4f acc[2][4];
    v4f zq[8];
    float v = 0.f;                         // LIF potential for h = tid
    int sprev = -1;                        // stripe whose z sits in zq

#define GEMM(BS) do {                                                     \
        _Pragma("unroll")                                                 \
        for (int _tt = 0; _tt < 2; _tt++) {                               \
            const int _ao = ((_tt * 4 + kg) * 16 + m16) * 8;              \
            const s8v _ah = *(const s8v*)&xfr[BS][0][_ao];                \
            const s8v _al = *(const s8v*)&xfr[BS][1][_ao];                \
            _Pragma("unroll")                                             \
            for (int _i = 0; _i < 4; _i++) {                              \
                acc[_tt][_i] = __builtin_amdgcn_mfma_f32_16x16x32_bf16(   \
                    _ah, whi[_i], acc[_tt][_i], 0, 0, 0);                 \
                acc[_tt][_i] = __builtin_amdgcn_mfma_f32_16x16x32_bf16(   \
                    _ah, wlo[_i], acc[_tt][_i], 0, 0, 0);                 \
                acc[_tt][_i] = __builtin_amdgcn_mfma_f32_16x16x32_bf16(   \
                    _al, whi[_i], acc[_tt][_i], 0, 0, 0);                 \
            }                                                             \
        }                                                                 \
    } while (0)

#define SCAN(S) do {                                                      \
        _Pragma("unroll")                                                 \
        for (int _c = 0; _c < 8; _c++) {                                  \
            _Pragma("unroll")                                             \
            for (int _u = 0; _u < 4; _u++) {                              \
                const float _z = zq[_c][_u];                              \
                v = v + (_z - v) * 0.5f;        /* charge (tau=2) */      \
                const bool _sp = v >= 1.0f;                               \
                const unsigned long long _m = __ballot(_sp);              \
                if (_sp) v = 0.0f;              /* hard reset */          \
                if (lane == 0)                                            \
                    bout[(size_t)((S) * TS + _c * 4 + _u) * 8] = _m;      \
            }                                                             \
        }                                                                 \
    } while (0)

    STAGE(0, 0);
    __syncthreads();

    for (int s = 0; s < NSTR; s++) {
        const int bs = s & 1;
        // acc init = bias (one bias per h, all 4 t-rows)
        #pragma unroll
        for (int tt = 0; tt < 2; tt++)
            #pragma unroll
            for (int i = 0; i < 4; i++)
                acc[tt][i] = v4f{biasv[i], biasv[i], biasv[i], biasv[i]};

        if (s + 1 < NSTR) STAGE(s + 1, bs ^ 1);   // writes other x buffer
        GEMM(bs);                                  // reads this x buffer
        if (sprev >= 0) SCAN(sprev);               // pure reg + global stores
        __syncthreads();                           // zq reads (s-1) done; stage done

        // acc -> z_lds  (D map: t = tt*16 + kg*4 + reg, h = (4w+i)*16 + m16)
        #pragma unroll
        for (int tt = 0; tt < 2; tt++)
            #pragma unroll
            for (int i = 0; i < 4; i++) {
                const int h = (w * 4 + i) * 16 + m16;
                *(v4f*)&zl[h][tt * 16 + kg * 4] = acc[tt][i];
            }
        __syncthreads();                           // z ready

        #pragma unroll
        for (int c = 0; c < 8; c++)                // z row for h = tid -> regs
            zq[c] = *(const v4f*)&zl[tid][c * 4];
        sprev = s;
    }
    SCAN(sprev);                                   // stripe 15
#undef SCAN
#undef GEMM
#undef STAGE
}

// ---------------------------------------------------------------------------
// tail: grid (NB, NGRP), 256 threads (r13's, unchanged except natural
// bitmap word order: word wi covers h in [64wi, 64wi+64)).
// ---------------------------------------------------------------------------
__global__ __launch_bounds__(256, 1) void tail_kernel(
    const uint64_t* __restrict__ bmg, // (NB, NT, 8)
    const v2f*  __restrict__ W2Tp,    // (HID d, 256 j) pairs
    const float* __restrict__ b2,     // (HID)
    float* __restrict__ gfeat)        // (NB, HID) accumulator
{
    __shared__ uint32_t sbuf[2][256];
    __shared__ uint4    evl[LMAXREC];
    __shared__ uint32_t nrec_s;

    const int b     = blockIdx.x;
    const int grp   = blockIdx.y;
    const int tid   = threadIdx.x;
    const int tmain = grp * CHUNK;
    const int ts    = (grp == 0) ? 0 : tmain - WARM;
    const int te    = tmain + CHUNK;
    const int nrow  = te - ts;

    uint64_t w0[8];
    int rcnt = 0;
    if (tid < nrow) {
        const uint4* p = (const uint4*)(bmg + ((size_t)b * NT + ts + tid) * 8);
        int cpop = 0;
        #pragma unroll
        for (int k = 0; k < 4; k++) {
            const uint4 q = p[k];
            w0[2 * k]     = (uint64_t)q.x | ((uint64_t)q.y << 32);
            w0[2 * k + 1] = (uint64_t)q.z | ((uint64_t)q.w << 32);
        }
        #pragma unroll
        for (int k = 0; k < 8; k++) cpop += __builtin_popcountll(w0[k]);
        rcnt = (cpop + 3) >> 2;
    }
    sbuf[0][tid] = (uint32_t)rcnt;
    __syncthreads();
    int cur = 0;
    for (int off = 1; off < 256; off <<= 1) {
        const uint32_t a = sbuf[cur][tid] + (tid >= off ? sbuf[cur][tid - off] : 0u);
        sbuf[cur ^ 1][tid] = a;
        __syncthreads();
        cur ^= 1;
    }
    const int excl = (int)sbuf[cur][tid] - rcnt;
    if (tid == 255) nrec_s = sbuf[cur][255];

    if (tid < nrow && rcnt) {
        const int t = ts + tid;
        int slot = excl, kk = 0; uint64_t ww = 0;
        #pragma unroll
        for (int wi = 0; wi < 8; wi++) {
            uint64_t wd = w0[wi];
            const int hbase = wi << 6;            // natural word order
            while (wd) {
                const int d = hbase + __builtin_ctzll(wd);
                wd &= wd - 1;
                ww |= (uint64_t)(uint32_t)d << (kk * 16);
                kk++;
                if (kk == 4) {
                    if (slot < LMAXREC) {
                        uint4 q; q.x = (uint32_t)(t | (4 << 16)); q.y = 0;
                        q.z = (uint32_t)ww; q.w = (uint32_t)(ww >> 32);
                        evl[slot] = q;
                    }
                    slot++; kk = 0; ww = 0;
                }
            }
        }
        if (kk && slot < LMAXREC) {
            uint4 q; q.x = (uint32_t)(t | (kk << 16)); q.y = 0;
            q.z = (uint32_t)ww; q.w = (uint32_t)(ww >> 32);
            evl[slot] = q;
        }
    }
    __syncthreads();

    const int nrec = (int)nrec_s < LMAXREC ? (int)nrec_s : LMAXREC;
    const float bb0 = b2[tid], bb1 = b2[tid + 256];
    float v0 = 0.f, v1 = 0.f;
    int cnt0 = 0, cnt1 = 0;
    int tprev = ts - 1;
    int pt = -1; v2f pg = {0.f, 0.f}; bool pend = false;

#define APPLY() do {                                                      \
        const int kk = pt - tprev - 1;                                    \
        if (kk > 0) { v0 = bb0 + ldexpf(v0 - bb0, -kk);                   \
                      v1 = bb1 + ldexpf(v1 - bb1, -kk); }                 \
        const float z0 = pg.x + bb0, z1 = pg.y + bb1;                     \
        v0 = v0 + (z0 - v0) * 0.5f;                                       \
        v1 = v1 + (z1 - v1) * 0.5f;                                       \
        if (v0 >= 1.0f) { if (pt >= tmain) cnt0++; v0 = 0.0f; }           \
        if (v1 >= 1.0f) { if (pt >= tmain) cnt1++; v1 = 0.0f; }           \
        tprev = pt;                                                       \
    } while (0)

    for (int base = 0; base < nrec; base += 8) {
        v2f g[8]; int tt[8];
        #pragma unroll
        for (int q = 0; q < 8; q++) {
            v2f gr = {0.f, 0.f}; int trr = -2;
            if (base + q < nrec) {
                const uint4 ev = evl[base + q];
                trr = (int)(ev.x & 511u);
                const int cc = (int)((ev.x >> 16) & 7u);
                const uint64_t ww = (uint64_t)ev.z | ((uint64_t)ev.w << 32);
                #pragma unroll
                for (int j = 0; j < 4; j++) {
                    const int d = (int)((ww >> (16 * j)) & 0xffffu);
                    const float mm = (j < cc) ? 1.0f : 0.0f;
                    const v2f wv = W2Tp[(size_t)d * 256 + tid];
                    gr = gr + v2f{mm, mm} * wv;
                }
            }
            g[q] = gr; tt[q] = trr;
        }
        #pragma unroll
        for (int q = 0; q < 8; q++) {
            if (base + q >= nrec) break;
            const int t = tt[q];
            if (pend && t == pt) { pg = pg + g[q]; }
            else { if (pend) APPLY(); pt = t; pg = g[q]; pend = true; }
        }
    }
    if (pend) APPLY();
#undef APPLY

    if (cnt0) atomicAdd(&gfeat[(size_t)b * HID + tid], (float)cnt0);
    if (cnt1) atomicAdd(&gfeat[(size_t)b * HID + 256 + tid], (float)cnt1);
}

// ---------------------------------------------------------------------------
// head: out = (gfeat/NT) @ Wh^T + bh. Grid NB, 256 threads.
// ---------------------------------------------------------------------------
__global__ __launch_bounds__(256) void head_kernel(
    const float* __restrict__ gfeat,
    const float* __restrict__ Wh,
    const float* __restrict__ bh,
    float* __restrict__ out)
{
    __shared__ float feat[HID];
    const int b = blockIdx.x;
    const int tid = threadIdx.x;
    const int lane = tid & 63;
    const int wg = tid >> 6;

    feat[tid]       = gfeat[(size_t)b * HID + tid]       * (1.0f / (float)NT);
    feat[tid + 256] = gfeat[(size_t)b * HID + 256 + tid] * (1.0f / (float)NT);
    __syncthreads();

    float acc[3] = {0.f, 0.f, 0.f};
    #pragma unroll
    for (int i = 0; i < HID / 64; i++) {
        const float f = feat[lane + i * 64];
        #pragma unroll
        for (int cc = 0; cc < 3; cc++)
            acc[cc] = fmaf(f, Wh[(size_t)(wg * 3 + cc) * HID + lane + i * 64], acc[cc]);
    }
    #pragma unroll
    for (int cc = 0; cc < 3; cc++) {
        float s = acc[cc];
        #pragma unroll
        for (int off = 32; off > 0; off >>= 1) s += __shfl_down(s, off);
        if (lane == 0) out[(size_t)b * NCLS + wg * 3 + cc] = s + bh[wg * 3 + cc];
    }
}

// ---------------------------------------------------------------------------
extern "C" void kernel_launch(void* const* d_in, const int* in_sizes, int n_in,
                              void* d_out, int out_size, void* d_ws, size_t ws_size,
                              hipStream_t stream) {
    const float* x  = (const float*)d_in[0];
    const float* W1 = (const float*)d_in[1];
    const float* b1 = (const float*)d_in[2];
    const float* W2 = (const float*)d_in[3];
    const float* b2 = (const float*)d_in[4];
    const float* Wh = (const float*)d_in[5];
    const float* bh = (const float*)d_in[6];
    float* out = (float*)d_out;

    // Workspace: W2Tp (1 MB) + bitmap (8 MB) + gfeat (512 KB).
    char* ws = (char*)d_ws;
    v2f*      W2Tp  = (v2f*)ws;
    uint64_t* bmg   = (uint64_t*)(ws + (1u << 20));
    float*    gfeat = (float*)(ws + (9u << 20));

    hipLaunchKernelGGL(w2pt_kernel, dim3(16, 8), dim3(256), 0, stream,
                       W2, W2Tp, gfeat);
    hipLaunchKernelGGL(lif1_mfma_kernel, dim3(NB), dim3(512), 0, stream,
                       x, W1, b1, bmg);
    hipLaunchKernelGGL(tail_kernel, dim3(NB, NGRP), dim3(256), 0, stream,
                       bmg, W2Tp, b2, gfeat);
    hipLaunchKernelGGL(head_kernel, dim3(NB), dim3(256), 0, stream,
                       gfeat, Wh, bh, out);
}